// Round 3
// baseline (1689.160 us; speedup 1.0000x reference)
//
#include <hip/hip_runtime.h>

typedef short short8 __attribute__((ext_vector_type(8)));
typedef float f4 __attribute__((ext_vector_type(4)));
typedef int i4 __attribute__((ext_vector_type(4)));
typedef _Float16 half8 __attribute__((ext_vector_type(8)));
typedef _Float16 h2 __attribute__((ext_vector_type(2)));

#define HD 256
#define ED 300
#define EP 320
#define TH 768
#define NS 1024
#define LW 64
#define SH 4.5f

__device__ __forceinline__ unsigned short f2bf(float f) {
    unsigned int u = __float_as_uint(f);
    u = (u + 0x7FFFu + ((u >> 16) & 1u)) >> 16;
    return (unsigned short)u;
}
__device__ __forceinline__ float bf2f(unsigned short s) {
    return __uint_as_float(((unsigned int)s) << 16);
}
__device__ __forceinline__ float sigm(float x) {
    return __builtin_amdgcn_rcpf(1.f + __expf(-x));
}
__device__ __forceinline__ float tanh_(float x) {
    x = fminf(fmaxf(x, -15.f), 15.f);
    return 1.f - 2.f * __builtin_amdgcn_rcpf(1.f + __expf(2.f * x));
}
__device__ __forceinline__ unsigned int pack_h2(float a, float b) {
    h2 p; p.x = (_Float16)a; p.y = (_Float16)b;
    return __builtin_bit_cast(unsigned int, p);
}

__device__ __forceinline__ void load8bf(const unsigned short* p, float* o) {
    uint4 a = *(const uint4*)p;
    o[0] = bf2f((unsigned short)(a.x & 0xffff)); o[1] = bf2f((unsigned short)(a.x >> 16));
    o[2] = bf2f((unsigned short)(a.y & 0xffff)); o[3] = bf2f((unsigned short)(a.y >> 16));
    o[4] = bf2f((unsigned short)(a.z & 0xffff)); o[5] = bf2f((unsigned short)(a.z >> 16));
    o[6] = bf2f((unsigned short)(a.w & 0xffff)); o[7] = bf2f((unsigned short)(a.w >> 16));
}
__device__ __forceinline__ void ubf4(uint2 a, float* o) {
    o[0] = bf2f((unsigned short)(a.x & 0xffff)); o[1] = bf2f((unsigned short)(a.x >> 16));
    o[2] = bf2f((unsigned short)(a.y & 0xffff)); o[3] = bf2f((unsigned short)(a.y >> 16));
}

// i8 dot4: d = sum(a.i8[i]*b.i8[i]) + c  (exact integer math)
__device__ __forceinline__ int dot4(int a, int b, int c) {
#if __has_builtin(__builtin_amdgcn_sdot4)
    return __builtin_amdgcn_sdot4(a, b, c, false);
#else
    int s = c;
    s += (int)(signed char)(a & 0xff)        * (int)(signed char)(b & 0xff);
    s += (int)(signed char)((a >> 8) & 0xff) * (int)(signed char)((b >> 8) & 0xff);
    s += (int)(signed char)((a >> 16) & 0xff)* (int)(signed char)((b >> 16) & 0xff);
    s += (int)(signed char)((a >> 24) & 0xff)* (int)(signed char)((b >> 24) & 0xff);
    return s;
#endif
}

// ---------------- prep: weight conversions, i8 quantization (ALL 768 Whh rows), Dq, topic ----------------
__global__ void k_prep(const float* __restrict__ W, const float* __restrict__ U,
                       const float* __restrict__ Wih, const float* __restrict__ Whh,
                       const float* __restrict__ q, const float* __restrict__ Dm,
                       const float* __restrict__ DT, const float* __restrict__ mlpW,
                       const float* __restrict__ mlpb,
                       const float* __restrict__ bih, const float* __restrict__ bhh,
                       unsigned short* __restrict__ Wb, _Float16* __restrict__ Uh,
                       _Float16* __restrict__ Wihh,
                       signed char* __restrict__ Wq, float* __restrict__ rowscale,
                       float* __restrict__ bias2,
                       float* __restrict__ Dq, float* __restrict__ tv) {
    __shared__ float smax[4];
    int bid = blockIdx.x, tid = threadIdx.x;
    if (bid < 768) {
        int r = bid;
        for (int j = tid; j < EP; j += 256)
            Wb[r * EP + j] = (j < ED) ? f2bf(W[r * ED + j]) : (unsigned short)0;
        float whv = Whh[r * HD + tid];
        for (int j = tid; j < HD; j += 256) {
            Uh[r * HD + j] = (_Float16)U[r * HD + j];
            Wihh[r * HD + j] = (_Float16)Wih[r * HD + j];
        }
        // per-row i8 quantization of ALL Whh rows
        float v = fabsf(whv);
        for (int o = 32; o; o >>= 1) v = fmaxf(v, __shfl_xor(v, o));
        if ((tid & 63) == 0) smax[tid >> 6] = v;
        __syncthreads();
        float am = fmaxf(fmaxf(smax[0], smax[1]), fmaxf(smax[2], smax[3]));
        float inv = (am > 0.f) ? 127.f / am : 0.f;
        int qi = (int)rintf(whv * inv);
        qi = max(-127, min(127, qi));
        Wq[r * HD + tid] = (signed char)qi;
        if (tid == 0) rowscale[r] = (am / 127.f) * (SH / 127.f);
    } else if (bid < 798) {
        int idx = bid - 768;
        int d = idx / 3, part = idx - d * 3;
        int n = part * 256 + tid;
        float s = 0.f;
        for (int h = 0; h < HD; ++h) s += Dm[n * HD + h] * q[d * HD + h];
        Dq[d * TH + n] = s;
    } else {
        if (tid < HD) {
            float s = 0.f;
            for (int k = 0; k < 100; ++k) s += mlpW[tid * 100 + k] * DT[k];
            tv[tid] = tanh_(s + mlpb[tid]);
        }
        for (int r = tid; r < TH; r += 256)
            bias2[r] = bih[r] + ((r < 512) ? bhh[r] : 0.f);
    }
}

// ---------------- phase B v2: x staged once in LDS as bf16; K-loop = ds_read + MFMA only ----------------
#define XP 328   // padded LDS row stride (elements); 328*2B/4 = 164 dwords, %32=4 -> 2-way alias (free)
__launch_bounds__(256, 2)
__global__ void k_phaseB(const int* __restrict__ sIdx, const int* __restrict__ depT,
                         const float* __restrict__ emb, const unsigned short* __restrict__ Wb,
                         const float* __restrict__ Dq, const float* __restrict__ bias,
                         unsigned short* __restrict__ pre) {
    __shared__ float dq_s[10 * 772];
    __shared__ float b_s[TH];
    __shared__ int dep_s[32];
    __shared__ int idx_s[32];
    __shared__ __align__(16) unsigned short xbf[32 * XP];
    int tid = threadIdx.x;
    int c0 = blockIdx.x * 32;
    for (int i = tid; i < 10 * 768; i += 256) {
        int d = i / 768, n = i - d * 768;
        dq_s[d * 772 + n] = Dq[i];
    }
    for (int i = tid; i < TH; i += 256) b_s[i] = bias[i];
    if (tid < 32) {
        int m = c0 + tid;
        idx_s[tid] = sIdx[m];
        int l = m & 63, s = m >> 6;
        dep_s[tid] = (l == 63) ? 9 : depT[s * 63 + l];
    }
    __syncthreads();
    // stage 32 gathered x rows as bf16 (coalesced within a row)
    for (int i = tid; i < 32 * EP; i += 256) {
        int row = i / EP, col = i - row * EP;
        unsigned short v = 0;
        if (col < ED) v = f2bf(emb[(long)idx_s[row] * ED + col]);
        xbf[row * XP + col] = v;
    }
    __syncthreads();

    int lane = tid & 63;
    int w = tid >> 6;
    int quad = lane >> 4, l16 = lane & 15;

    f4 acc[2][12];
#pragma unroll
    for (int cs = 0; cs < 2; ++cs)
#pragma unroll
        for (int ms = 0; ms < 12; ++ms) acc[cs][ms] = (f4){0.f, 0.f, 0.f, 0.f};

    const unsigned short* wbase = Wb + (w * 192 + l16) * EP;

#pragma unroll
    for (int kt = 0; kt < 10; ++kt) {
        int k0 = kt * 32 + quad * 8;
        short8 bf0 = *(const short8*)&xbf[l16 * XP + k0];
        short8 bf1 = *(const short8*)&xbf[(16 + l16) * XP + k0];
#pragma unroll
        for (int ms = 0; ms < 12; ++ms) {
            short8 af = *(const short8*)(wbase + ms * 16 * EP + k0);
            acc[0][ms] = __builtin_amdgcn_mfma_f32_16x16x32_bf16(af, bf0, acc[0][ms], 0, 0, 0);
            acc[1][ms] = __builtin_amdgcn_mfma_f32_16x16x32_bf16(af, bf1, acc[1][ms], 0, 0, 0);
        }
    }

#pragma unroll
    for (int cs = 0; cs < 2; ++cs) {
        int xr = c0 + cs * 16 + l16;
        int dep = dep_s[cs * 16 + l16];
        unsigned short* prow = pre + (long)xr * TH;
#pragma unroll
        for (int ms = 0; ms < 12; ++ms) {
            int ncol = w * 192 + ms * 16 + quad * 4;
            f4 dq4 = *(const f4*)&dq_s[dep * 772 + ncol];
            f4 b4 = *(const f4*)&b_s[ncol];
            unsigned int lo = (unsigned int)f2bf(acc[cs][ms][0] + dq4[0] + b4[0]) |
                              ((unsigned int)f2bf(acc[cs][ms][1] + dq4[1] + b4[1]) << 16);
            unsigned int hi = (unsigned int)f2bf(acc[cs][ms][2] + dq4[2] + b4[2]) |
                              ((unsigned int)f2bf(acc[cs][ms][3] + dq4[3] + b4[3]) << 16);
            uint2 v; v.x = lo; v.y = hi;
            *(uint2*)(prow + ncol) = v;
        }
    }
}

// ---------------- phase C: U AGPR-resident MFMA, 16 sentences/WG, pre-loads hoisted ----------------
__global__ void __launch_bounds__(768) k_phaseC(
                         const unsigned short* __restrict__ pre,
                         const _Float16* __restrict__ Uh,
                         const _Float16* __restrict__ Wihh,
                         const float* __restrict__ bias2,
                         float* __restrict__ gi) {
    __shared__ __align__(16) uint4 hfr[512];
    __shared__ __align__(16) float tot[16 * 772];
    int tid = threadIdx.x;
    int lane = tid & 63, w = tid >> 6, quad = lane >> 4, l16 = lane & 15;
    int s0 = blockIdx.x * 16;

    uint4 frag[32];
    {
        const _Float16* base = Uh + (w * 64 + l16) * HD;
#pragma unroll
        for (int t = 0; t < 4; ++t)
#pragma unroll
            for (int kt = 0; kt < 8; ++kt)
                frag[t * 8 + kt] = *(const uint4*)(base + t * 16 * HD + kt * 32 + quad * 8);
    }

    int us = tid >> 5;
    int jg = tid & 31;
    int j0 = jg * 8;
    int hcell = (j0 >> 5) * 64 + 16 * ((j0 >> 3) & 3) + us;
    uint4 hcp;

    if (tid < 512) {
        const unsigned short* prow = pre + ((long)(s0 + us) * LW + 63) * TH;
        float iv[8], uv[8], hcv[8];
        load8bf(prow + 256 + j0, iv);
        load8bf(prow + 512 + j0, uv);
#pragma unroll
        for (int r = 0; r < 8; ++r) hcv[r] = tanh_(sigm(iv[r]) * tanh_(uv[r]));
        hcp.x = pack_h2(hcv[0], hcv[1]); hcp.y = pack_h2(hcv[2], hcv[3]);
        hcp.z = pack_h2(hcv[4], hcv[5]); hcp.w = pack_h2(hcv[6], hcv[7]);
        hfr[hcell] = hcp;
    }
    __syncthreads();

    int mb = w * 64 + quad * 4;

    for (int step = 0; step < 63; ++step) {
        int l = 62 - step;
        uint2 praw[6];
        if (tid < 512) {
            const unsigned short* prow = pre + ((long)(s0 + us) * LW + l) * TH;
#pragma unroll
            for (int g = 0; g < 3; ++g) {
                praw[2 * g]     = *(const uint2*)(prow + g * 256 + j0);
                praw[2 * g + 1] = *(const uint2*)(prow + g * 256 + j0 + 4);
            }
        }
        f4 a0 = (f4){0,0,0,0}, a1 = (f4){0,0,0,0}, a2 = (f4){0,0,0,0}, a3 = (f4){0,0,0,0};
#pragma unroll
        for (int kt = 0; kt < 8; ++kt) {
            half8 b = __builtin_bit_cast(half8, hfr[kt * 64 + lane]);
            a0 = __builtin_amdgcn_mfma_f32_16x16x32_f16(__builtin_bit_cast(half8, frag[kt]), b, a0, 0, 0, 0);
            a1 = __builtin_amdgcn_mfma_f32_16x16x32_f16(__builtin_bit_cast(half8, frag[8 + kt]), b, a1, 0, 0, 0);
            a2 = __builtin_amdgcn_mfma_f32_16x16x32_f16(__builtin_bit_cast(half8, frag[16 + kt]), b, a2, 0, 0, 0);
            a3 = __builtin_amdgcn_mfma_f32_16x16x32_f16(__builtin_bit_cast(half8, frag[24 + kt]), b, a3, 0, 0, 0);
        }
        float* tr = tot + l16 * 772;
        *(f4*)&tr[mb] = a0;
        *(f4*)&tr[mb + 16] = a1;
        *(f4*)&tr[mb + 32] = a2;
        *(f4*)&tr[mb + 48] = a3;
        __syncthreads();
        if (tid < 512) {
            const float* ts = tot + us * 772;
            float hcv[8];
            h2 px = __builtin_bit_cast(h2, hcp.x); h2 py = __builtin_bit_cast(h2, hcp.y);
            h2 pz = __builtin_bit_cast(h2, hcp.z); h2 pw = __builtin_bit_cast(h2, hcp.w);
            hcv[0] = (float)px.x; hcv[1] = (float)px.y; hcv[2] = (float)py.x; hcv[3] = (float)py.y;
            hcv[4] = (float)pz.x; hcv[5] = (float)pz.y; hcv[6] = (float)pw.x; hcv[7] = (float)pw.y;
#pragma unroll
            for (int hf = 0; hf < 2; ++hf) {
                int jb = j0 + hf * 4;
                float pf[4], pi_[4], pu[4];
                ubf4(praw[hf], pf);
                ubf4(praw[2 + hf], pi_);
                ubf4(praw[4 + hf], pu);
                f4 tf = *(const f4*)&ts[jb];
                f4 ti = *(const f4*)&ts[256 + jb];
                f4 tu = *(const f4*)&ts[512 + jb];
#pragma unroll
                for (int r = 0; r < 4; ++r) {
                    float ff = tf[r] + pf[r];
                    float ii = ti[r] + pi_[r];
                    float uu = tu[r] + pu[r];
                    hcv[hf * 4 + r] = tanh_(sigm(ii) * tanh_(uu) + sigm(ff) * hcv[hf * 4 + r]);
                }
            }
            hcp.x = pack_h2(hcv[0], hcv[1]); hcp.y = pack_h2(hcv[2], hcv[3]);
            hcp.z = pack_h2(hcv[4], hcv[5]); hcp.w = pack_h2(hcv[6], hcv[7]);
            hfr[hcell] = hcp;
        }
        __syncthreads();
    }

    {
        const _Float16* base = Wihh + (w * 64 + l16) * HD;
#pragma unroll
        for (int t = 0; t < 4; ++t)
#pragma unroll
            for (int kt = 0; kt < 8; ++kt)
                frag[t * 8 + kt] = *(const uint4*)(base + t * 16 * HD + kt * 32 + quad * 8);
    }
    f4 a0 = (f4){0,0,0,0}, a1 = (f4){0,0,0,0}, a2 = (f4){0,0,0,0}, a3 = (f4){0,0,0,0};
#pragma unroll
    for (int kt = 0; kt < 8; ++kt) {
        half8 b = __builtin_bit_cast(half8, hfr[kt * 64 + lane]);
        a0 = __builtin_amdgcn_mfma_f32_16x16x32_f16(__builtin_bit_cast(half8, frag[kt]), b, a0, 0, 0, 0);
        a1 = __builtin_amdgcn_mfma_f32_16x16x32_f16(__builtin_bit_cast(half8, frag[8 + kt]), b, a1, 0, 0, 0);
        a2 = __builtin_amdgcn_mfma_f32_16x16x32_f16(__builtin_bit_cast(half8, frag[16 + kt]), b, a2, 0, 0, 0);
        a3 = __builtin_amdgcn_mfma_f32_16x16x32_f16(__builtin_bit_cast(half8, frag[24 + kt]), b, a3, 0, 0, 0);
    }
    float* go = gi + (long)(s0 + l16) * TH;
    f4 b0 = *(const f4*)(bias2 + mb);
    f4 b1 = *(const f4*)(bias2 + mb + 16);
    f4 b2 = *(const f4*)(bias2 + mb + 32);
    f4 b3 = *(const f4*)(bias2 + mb + 48);
    *(f4*)(go + mb) = a0 + b0;
    *(f4*)(go + mb + 16) = a1 + b1;
    *(f4*)(go + mb + 32) = a2 + b2;
    *(f4*)(go + mb + 48) = a3 + b3;
}

// ---------------- GRU v12: dot4 matvec (zero N-waste), 768 threads = 1 row/lane ----------------
// MFMA matvec wasted 15/16 of the tile (B columns all carry the same h): 200 MACs/cy/CU.
// v_dot4_i32_i8 with 1 row/lane: 64 dot4/lane, 192 instr/SIMD * 2cy = 512 MACs/cy/CU (2.56x),
// identical int8 numerics (same quantization, exact integer dot). Also kills the 21-cndmask
// accumulator select (lane's dot result IS its row) and the 96-VGPR A-fragments.
// Step: [dot+fold -> sums LDS] bar [256 owners: gates, write h bytes] bar. gi load issues at
// phase top, consumed at fold (~400cy later) - hidden without cross-barrier prefetch.
__global__ void __launch_bounds__(768) k_gru(
                      const signed char* __restrict__ Wq, const float* __restrict__ rowscale,
                      const float* __restrict__ bhh,
                      const float* __restrict__ gi, const float* __restrict__ h0,
                      const float* __restrict__ tv,
                      const float* __restrict__ gateW, const float* __restrict__ gateU,
                      const float* __restrict__ gateb,
                      const float* __restrict__ outW, const float* __restrict__ outb,
                      float* __restrict__ out) {
    __shared__ __align__(16) int qd[2][64];   // h as 64 packed-i8 dwords, ping-pong
    __shared__ float sums[TH];                // folded r,z premult + npre
    __shared__ float gns[HD];                 // gn for owners
    __shared__ float hts[HD];
    __shared__ float sgs[512];
    __shared__ float vvs[HD];
    __shared__ float lg[8];

    int tid = threadIdx.x;
    int row = tid;                 // 0..767: rows 0-255 r, 256-511 z, 512-767 n
    bool isn = (row >= 512);
    bool owner = (row < HD);

    // preload this row's i8 weights into 64 VGPRs (one-time, amortized over 1024 steps)
    i4 wv[16];
    {
        const signed char* wr = Wq + (long)row * HD;
#pragma unroll
        for (int c = 0; c < 16; ++c) wv[c] = *(const i4*)(wr + c * 16);
    }
    float rs = rowscale[row];
    float bn = isn ? bhh[row] : 0.f;

    float hv = owner ? h0[row] : 0.f;
    if (owner) {
        float hc = fminf(fmaxf(hv, -SH), SH);
        ((signed char*)qd[0])[row] = (signed char)(int)rintf(hc * (127.f / SH));
    }
    __syncthreads();

    const float* gbase = gi + row;
    for (int t = 0; t < NS; ++t) {
        int p = t & 1;
        float gv = gbase[(long)t * TH];       // issued here, consumed at fold below
        int acc = 0;
#pragma unroll
        for (int c = 0; c < 16; ++c) {
            i4 hb = *(const i4*)&qd[p][c * 4];   // wave-uniform address: broadcast read
            acc = dot4(hb[0], wv[c][0], acc);
            acc = dot4(hb[1], wv[c][1], acc);
            acc = dot4(hb[2], wv[c][2], acc);
            acc = dot4(hb[3], wv[c][3], acc);
        }
        float fv = (float)acc * rs;
        sums[row] = isn ? (fv + bn) : (fv + gv);
        if (isn) gns[row - 512] = gv;
        __syncthreads();
        if (owner) {
            float rv = sigm(sums[row]);
            float zv = sigm(sums[HD + row]);
            float nv = tanh_(gns[row] + rv * sums[512 + row]);
            hv = (1.f - zv) * nv + zv * hv;
            float hc = fminf(fmaxf(hv, -SH), SH);
            ((signed char*)qd[p ^ 1])[row] = (signed char)(int)rintf(hc * (127.f / SH));
        }
        __syncthreads();
    }

    // head
    if (owner) hts[row] = hv;
    __syncthreads();
    if (tid < 512) {
        float s = gateb[tid];
        for (int k = 0; k < HD; ++k)
            s += gateW[tid * HD + k] * hts[k] + gateU[tid * HD + k] * tv[k];
        sgs[tid] = sigm(s);
    }
    __syncthreads();
    if (tid < HD) vvs[tid] = tanh_(sgs[tid] * hts[tid] + sgs[256 + tid] * tv[tid]);
    __syncthreads();
    if (tid < 5) {
        float s = outb[tid];
        for (int k = 0; k < HD; ++k) s += outW[tid * HD + k] * vvs[k];
        lg[tid] = s;
    }
    __syncthreads();
    if (tid == 0) {
        float m = lg[0];
        for (int i = 1; i < 5; ++i) m = fmaxf(m, lg[i]);
        float e[5], sum = 0.f;
        for (int i = 0; i < 5; ++i) { e[i] = __expf(lg[i] - m); sum += e[i]; }
        for (int i = 0; i < 5; ++i) out[i] = e[i] / sum;
    }
}

extern "C" void kernel_launch(void* const* d_in, const int* in_sizes, int n_in,
                              void* d_out, int out_size, void* d_ws, size_t ws_size,
                              hipStream_t stream) {
    (void)in_sizes; (void)n_in; (void)out_size; (void)ws_size;
    const int* sIdx = (const int*)d_in[0];
    const int* depT = (const int*)d_in[1];
    const float* DT = (const float*)d_in[2];
    const float* h0 = (const float*)d_in[3];
    const float* emb = (const float*)d_in[4];
    const float* q = (const float*)d_in[5];
    const float* W = (const float*)d_in[6];
    const float* U = (const float*)d_in[7];
    const float* Dm = (const float*)d_in[8];
    const float* b = (const float*)d_in[9];
    const float* Wih = (const float*)d_in[10];
    const float* Whh = (const float*)d_in[11];
    const float* bih = (const float*)d_in[12];
    const float* bhh = (const float*)d_in[13];
    const float* gateW = (const float*)d_in[14];
    const float* gateU = (const float*)d_in[15];
    const float* gateb = (const float*)d_in[16];
    const float* mlpW = (const float*)d_in[17];
    const float* mlpb = (const float*)d_in[18];
    const float* outW = (const float*)d_in[19];
    const float* outb = (const float*)d_in[20];

    char* ws = (char*)d_ws;
    unsigned short* Wb = (unsigned short*)ws;   ws += 768 * 320 * 2;
    _Float16* Uh = (_Float16*)ws;               ws += 768 * 256 * 2;
    _Float16* Wihh = (_Float16*)ws;             ws += 768 * 256 * 2;
    signed char* Wq = (signed char*)ws;         ws += 768 * 256;
    float* rowscale = (float*)ws;               ws += 768 * 4;
    float* bias2 = (float*)ws;                  ws += 768 * 4;
    float* Dq = (float*)ws;                     ws += 10 * 768 * 4;
    float* tv = (float*)ws;                     ws += 1024;
    ws = (char*)d_ws + ((((size_t)(ws - (char*)d_ws)) + 4095) & ~(size_t)4095);
    unsigned short* pre = (unsigned short*)ws;  ws += (size_t)65536 * 768 * 2;
    float* gi = (float*)ws;                     ws += (size_t)1024 * 768 * 4;

    k_prep<<<dim3(799), dim3(256), 0, stream>>>(W, U, Wih, Whh, q, Dm, DT, mlpW, mlpb,
                                                bih, bhh,
                                                Wb, Uh, Wihh, Wq, rowscale, bias2, Dq, tv);
    k_phaseB<<<dim3(2048), dim3(256), 0, stream>>>(sIdx, depT, emb, Wb, Dq, b, pre);
    k_phaseC<<<dim3(64), dim3(768), 0, stream>>>(pre, Uh, Wihh, bias2, gi);
    k_gru<<<dim3(1), dim3(768), 0, stream>>>(Wq, rowscale, bhh, gi, h0, tv,
                                             gateW, gateU, gateb, outW, outb, (float*)d_out);
}

// Round 4
// 1324.322 us; speedup vs baseline: 1.2755x; 1.2755x over previous
//
#include <hip/hip_runtime.h>

typedef short short8 __attribute__((ext_vector_type(8)));
typedef float f4 __attribute__((ext_vector_type(4)));
typedef int i4 __attribute__((ext_vector_type(4)));
typedef _Float16 half8 __attribute__((ext_vector_type(8)));
typedef _Float16 h2 __attribute__((ext_vector_type(2)));

#define HD 256
#define ED 300
#define EP 320
#define TH 768
#define NS 1024
#define LW 64
#define SH 4.5f

__device__ __forceinline__ unsigned short f2bf(float f) {
    unsigned int u = __float_as_uint(f);
    u = (u + 0x7FFFu + ((u >> 16) & 1u)) >> 16;
    return (unsigned short)u;
}
__device__ __forceinline__ float bf2f(unsigned short s) {
    return __uint_as_float(((unsigned int)s) << 16);
}
__device__ __forceinline__ float sigm(float x) {
    return __builtin_amdgcn_rcpf(1.f + __expf(-x));
}
__device__ __forceinline__ float tanh_(float x) {
    x = fminf(fmaxf(x, -15.f), 15.f);
    return 1.f - 2.f * __builtin_amdgcn_rcpf(1.f + __expf(2.f * x));
}
__device__ __forceinline__ unsigned int pack_h2(float a, float b) {
    h2 p; p.x = (_Float16)a; p.y = (_Float16)b;
    return __builtin_bit_cast(unsigned int, p);
}

__device__ __forceinline__ void load8bf(const unsigned short* p, float* o) {
    uint4 a = *(const uint4*)p;
    o[0] = bf2f((unsigned short)(a.x & 0xffff)); o[1] = bf2f((unsigned short)(a.x >> 16));
    o[2] = bf2f((unsigned short)(a.y & 0xffff)); o[3] = bf2f((unsigned short)(a.y >> 16));
    o[4] = bf2f((unsigned short)(a.z & 0xffff)); o[5] = bf2f((unsigned short)(a.z >> 16));
    o[6] = bf2f((unsigned short)(a.w & 0xffff)); o[7] = bf2f((unsigned short)(a.w >> 16));
}
__device__ __forceinline__ void ubf4(uint2 a, float* o) {
    o[0] = bf2f((unsigned short)(a.x & 0xffff)); o[1] = bf2f((unsigned short)(a.x >> 16));
    o[2] = bf2f((unsigned short)(a.y & 0xffff)); o[3] = bf2f((unsigned short)(a.y >> 16));
}

// i8 dot4: d = sum(a.i8[i]*b.i8[i]) + c  (exact integer math)
__device__ __forceinline__ int dot4(int a, int b, int c) {
#if __has_builtin(__builtin_amdgcn_sdot4)
    return __builtin_amdgcn_sdot4(a, b, c, false);
#else
    int s = c;
    s += (int)(signed char)(a & 0xff)        * (int)(signed char)(b & 0xff);
    s += (int)(signed char)((a >> 8) & 0xff) * (int)(signed char)((b >> 8) & 0xff);
    s += (int)(signed char)((a >> 16) & 0xff)* (int)(signed char)((b >> 16) & 0xff);
    s += (int)(signed char)((a >> 24) & 0xff)* (int)(signed char)((b >> 24) & 0xff);
    return s;
#endif
}

// ---------------- prep: weight conversions, i8 quantization (ALL 768 Whh rows), Dq, topic ----------------
__global__ void k_prep(const float* __restrict__ W, const float* __restrict__ U,
                       const float* __restrict__ Wih, const float* __restrict__ Whh,
                       const float* __restrict__ q, const float* __restrict__ Dm,
                       const float* __restrict__ DT, const float* __restrict__ mlpW,
                       const float* __restrict__ mlpb,
                       const float* __restrict__ bih, const float* __restrict__ bhh,
                       unsigned short* __restrict__ Wb, _Float16* __restrict__ Uh,
                       _Float16* __restrict__ Wihh,
                       signed char* __restrict__ Wq, float* __restrict__ rowscale,
                       float* __restrict__ bias2,
                       float* __restrict__ Dq, float* __restrict__ tv) {
    __shared__ float smax[4];
    int bid = blockIdx.x, tid = threadIdx.x;
    if (bid < 768) {
        int r = bid;
        for (int j = tid; j < EP; j += 256)
            Wb[r * EP + j] = (j < ED) ? f2bf(W[r * ED + j]) : (unsigned short)0;
        float whv = Whh[r * HD + tid];
        for (int j = tid; j < HD; j += 256) {
            Uh[r * HD + j] = (_Float16)U[r * HD + j];
            Wihh[r * HD + j] = (_Float16)Wih[r * HD + j];
        }
        // per-row i8 quantization of ALL Whh rows
        float v = fabsf(whv);
        for (int o = 32; o; o >>= 1) v = fmaxf(v, __shfl_xor(v, o));
        if ((tid & 63) == 0) smax[tid >> 6] = v;
        __syncthreads();
        float am = fmaxf(fmaxf(smax[0], smax[1]), fmaxf(smax[2], smax[3]));
        float inv = (am > 0.f) ? 127.f / am : 0.f;
        int qi = (int)rintf(whv * inv);
        qi = max(-127, min(127, qi));
        Wq[r * HD + tid] = (signed char)qi;
        if (tid == 0) rowscale[r] = (am / 127.f) * (SH / 127.f);
    } else if (bid < 798) {
        int idx = bid - 768;
        int d = idx / 3, part = idx - d * 3;
        int n = part * 256 + tid;
        float s = 0.f;
        for (int h = 0; h < HD; ++h) s += Dm[n * HD + h] * q[d * HD + h];
        Dq[d * TH + n] = s;
    } else {
        if (tid < HD) {
            float s = 0.f;
            for (int k = 0; k < 100; ++k) s += mlpW[tid * 100 + k] * DT[k];
            tv[tid] = tanh_(s + mlpb[tid]);
        }
        for (int r = tid; r < TH; r += 256)
            bias2[r] = bih[r] + ((r < 512) ? bhh[r] : 0.f);
    }
}

// ---------------- phase B v2: x staged once in LDS as bf16; K-loop = ds_read + MFMA only ----------------
#define XP 328   // padded LDS row stride (elements); 328*2B/4 = 164 dwords, %32=4 -> 2-way alias (free)
__launch_bounds__(256, 2)
__global__ void k_phaseB(const int* __restrict__ sIdx, const int* __restrict__ depT,
                         const float* __restrict__ emb, const unsigned short* __restrict__ Wb,
                         const float* __restrict__ Dq, const float* __restrict__ bias,
                         unsigned short* __restrict__ pre) {
    __shared__ float dq_s[10 * 772];
    __shared__ float b_s[TH];
    __shared__ int dep_s[32];
    __shared__ int idx_s[32];
    __shared__ __align__(16) unsigned short xbf[32 * XP];
    int tid = threadIdx.x;
    int c0 = blockIdx.x * 32;
    for (int i = tid; i < 10 * 768; i += 256) {
        int d = i / 768, n = i - d * 768;
        dq_s[d * 772 + n] = Dq[i];
    }
    for (int i = tid; i < TH; i += 256) b_s[i] = bias[i];
    if (tid < 32) {
        int m = c0 + tid;
        idx_s[tid] = sIdx[m];
        int l = m & 63, s = m >> 6;
        dep_s[tid] = (l == 63) ? 9 : depT[s * 63 + l];
    }
    __syncthreads();
    // stage 32 gathered x rows as bf16 (coalesced within a row)
    for (int i = tid; i < 32 * EP; i += 256) {
        int row = i / EP, col = i - row * EP;
        unsigned short v = 0;
        if (col < ED) v = f2bf(emb[(long)idx_s[row] * ED + col]);
        xbf[row * XP + col] = v;
    }
    __syncthreads();

    int lane = tid & 63;
    int w = tid >> 6;
    int quad = lane >> 4, l16 = lane & 15;

    f4 acc[2][12];
#pragma unroll
    for (int cs = 0; cs < 2; ++cs)
#pragma unroll
        for (int ms = 0; ms < 12; ++ms) acc[cs][ms] = (f4){0.f, 0.f, 0.f, 0.f};

    const unsigned short* wbase = Wb + (w * 192 + l16) * EP;

#pragma unroll
    for (int kt = 0; kt < 10; ++kt) {
        int k0 = kt * 32 + quad * 8;
        short8 bf0 = *(const short8*)&xbf[l16 * XP + k0];
        short8 bf1 = *(const short8*)&xbf[(16 + l16) * XP + k0];
#pragma unroll
        for (int ms = 0; ms < 12; ++ms) {
            short8 af = *(const short8*)(wbase + ms * 16 * EP + k0);
            acc[0][ms] = __builtin_amdgcn_mfma_f32_16x16x32_bf16(af, bf0, acc[0][ms], 0, 0, 0);
            acc[1][ms] = __builtin_amdgcn_mfma_f32_16x16x32_bf16(af, bf1, acc[1][ms], 0, 0, 0);
        }
    }

#pragma unroll
    for (int cs = 0; cs < 2; ++cs) {
        int xr = c0 + cs * 16 + l16;
        int dep = dep_s[cs * 16 + l16];
        unsigned short* prow = pre + (long)xr * TH;
#pragma unroll
        for (int ms = 0; ms < 12; ++ms) {
            int ncol = w * 192 + ms * 16 + quad * 4;
            f4 dq4 = *(const f4*)&dq_s[dep * 772 + ncol];
            f4 b4 = *(const f4*)&b_s[ncol];
            unsigned int lo = (unsigned int)f2bf(acc[cs][ms][0] + dq4[0] + b4[0]) |
                              ((unsigned int)f2bf(acc[cs][ms][1] + dq4[1] + b4[1]) << 16);
            unsigned int hi = (unsigned int)f2bf(acc[cs][ms][2] + dq4[2] + b4[2]) |
                              ((unsigned int)f2bf(acc[cs][ms][3] + dq4[3] + b4[3]) << 16);
            uint2 v; v.x = lo; v.y = hi;
            *(uint2*)(prow + ncol) = v;
        }
    }
}

// ---------------- phase C: U AGPR-resident MFMA, 16 sentences/WG, pre-loads hoisted ----------------
__global__ void __launch_bounds__(768) k_phaseC(
                         const unsigned short* __restrict__ pre,
                         const _Float16* __restrict__ Uh,
                         const _Float16* __restrict__ Wihh,
                         const float* __restrict__ bias2,
                         float* __restrict__ gi) {
    __shared__ __align__(16) uint4 hfr[512];
    __shared__ __align__(16) float tot[16 * 772];
    int tid = threadIdx.x;
    int lane = tid & 63, w = tid >> 6, quad = lane >> 4, l16 = lane & 15;
    int s0 = blockIdx.x * 16;

    uint4 frag[32];
    {
        const _Float16* base = Uh + (w * 64 + l16) * HD;
#pragma unroll
        for (int t = 0; t < 4; ++t)
#pragma unroll
            for (int kt = 0; kt < 8; ++kt)
                frag[t * 8 + kt] = *(const uint4*)(base + t * 16 * HD + kt * 32 + quad * 8);
    }

    int us = tid >> 5;
    int jg = tid & 31;
    int j0 = jg * 8;
    int hcell = (j0 >> 5) * 64 + 16 * ((j0 >> 3) & 3) + us;
    uint4 hcp;

    if (tid < 512) {
        const unsigned short* prow = pre + ((long)(s0 + us) * LW + 63) * TH;
        float iv[8], uv[8], hcv[8];
        load8bf(prow + 256 + j0, iv);
        load8bf(prow + 512 + j0, uv);
#pragma unroll
        for (int r = 0; r < 8; ++r) hcv[r] = tanh_(sigm(iv[r]) * tanh_(uv[r]));
        hcp.x = pack_h2(hcv[0], hcv[1]); hcp.y = pack_h2(hcv[2], hcv[3]);
        hcp.z = pack_h2(hcv[4], hcv[5]); hcp.w = pack_h2(hcv[6], hcv[7]);
        hfr[hcell] = hcp;
    }
    __syncthreads();

    int mb = w * 64 + quad * 4;

    for (int step = 0; step < 63; ++step) {
        int l = 62 - step;
        uint2 praw[6];
        if (tid < 512) {
            const unsigned short* prow = pre + ((long)(s0 + us) * LW + l) * TH;
#pragma unroll
            for (int g = 0; g < 3; ++g) {
                praw[2 * g]     = *(const uint2*)(prow + g * 256 + j0);
                praw[2 * g + 1] = *(const uint2*)(prow + g * 256 + j0 + 4);
            }
        }
        f4 a0 = (f4){0,0,0,0}, a1 = (f4){0,0,0,0}, a2 = (f4){0,0,0,0}, a3 = (f4){0,0,0,0};
#pragma unroll
        for (int kt = 0; kt < 8; ++kt) {
            half8 b = __builtin_bit_cast(half8, hfr[kt * 64 + lane]);
            a0 = __builtin_amdgcn_mfma_f32_16x16x32_f16(__builtin_bit_cast(half8, frag[kt]), b, a0, 0, 0, 0);
            a1 = __builtin_amdgcn_mfma_f32_16x16x32_f16(__builtin_bit_cast(half8, frag[8 + kt]), b, a1, 0, 0, 0);
            a2 = __builtin_amdgcn_mfma_f32_16x16x32_f16(__builtin_bit_cast(half8, frag[16 + kt]), b, a2, 0, 0, 0);
            a3 = __builtin_amdgcn_mfma_f32_16x16x32_f16(__builtin_bit_cast(half8, frag[24 + kt]), b, a3, 0, 0, 0);
        }
        float* tr = tot + l16 * 772;
        *(f4*)&tr[mb] = a0;
        *(f4*)&tr[mb + 16] = a1;
        *(f4*)&tr[mb + 32] = a2;
        *(f4*)&tr[mb + 48] = a3;
        __syncthreads();
        if (tid < 512) {
            const float* ts = tot + us * 772;
            float hcv[8];
            h2 px = __builtin_bit_cast(h2, hcp.x); h2 py = __builtin_bit_cast(h2, hcp.y);
            h2 pz = __builtin_bit_cast(h2, hcp.z); h2 pw = __builtin_bit_cast(h2, hcp.w);
            hcv[0] = (float)px.x; hcv[1] = (float)px.y; hcv[2] = (float)py.x; hcv[3] = (float)py.y;
            hcv[4] = (float)pz.x; hcv[5] = (float)pz.y; hcv[6] = (float)pw.x; hcv[7] = (float)pw.y;
#pragma unroll
            for (int hf = 0; hf < 2; ++hf) {
                int jb = j0 + hf * 4;
                float pf[4], pi_[4], pu[4];
                ubf4(praw[hf], pf);
                ubf4(praw[2 + hf], pi_);
                ubf4(praw[4 + hf], pu);
                f4 tf = *(const f4*)&ts[jb];
                f4 ti = *(const f4*)&ts[256 + jb];
                f4 tu = *(const f4*)&ts[512 + jb];
#pragma unroll
                for (int r = 0; r < 4; ++r) {
                    float ff = tf[r] + pf[r];
                    float ii = ti[r] + pi_[r];
                    float uu = tu[r] + pu[r];
                    hcv[hf * 4 + r] = tanh_(sigm(ii) * tanh_(uu) + sigm(ff) * hcv[hf * 4 + r]);
                }
            }
            hcp.x = pack_h2(hcv[0], hcv[1]); hcp.y = pack_h2(hcv[2], hcv[3]);
            hcp.z = pack_h2(hcv[4], hcv[5]); hcp.w = pack_h2(hcv[6], hcv[7]);
            hfr[hcell] = hcp;
        }
        __syncthreads();
    }

    {
        const _Float16* base = Wihh + (w * 64 + l16) * HD;
#pragma unroll
        for (int t = 0; t < 4; ++t)
#pragma unroll
            for (int kt = 0; kt < 8; ++kt)
                frag[t * 8 + kt] = *(const uint4*)(base + t * 16 * HD + kt * 32 + quad * 8);
    }
    f4 a0 = (f4){0,0,0,0}, a1 = (f4){0,0,0,0}, a2 = (f4){0,0,0,0}, a3 = (f4){0,0,0,0};
#pragma unroll
    for (int kt = 0; kt < 8; ++kt) {
        half8 b = __builtin_bit_cast(half8, hfr[kt * 64 + lane]);
        a0 = __builtin_amdgcn_mfma_f32_16x16x32_f16(__builtin_bit_cast(half8, frag[kt]), b, a0, 0, 0, 0);
        a1 = __builtin_amdgcn_mfma_f32_16x16x32_f16(__builtin_bit_cast(half8, frag[8 + kt]), b, a1, 0, 0, 0);
        a2 = __builtin_amdgcn_mfma_f32_16x16x32_f16(__builtin_bit_cast(half8, frag[16 + kt]), b, a2, 0, 0, 0);
        a3 = __builtin_amdgcn_mfma_f32_16x16x32_f16(__builtin_bit_cast(half8, frag[24 + kt]), b, a3, 0, 0, 0);
    }
    float* go = gi + (long)(s0 + l16) * TH;
    f4 b0 = *(const f4*)(bias2 + mb);
    f4 b1 = *(const f4*)(bias2 + mb + 16);
    f4 b2 = *(const f4*)(bias2 + mb + 32);
    f4 b3 = *(const f4*)(bias2 + mb + 48);
    *(f4*)(go + mb) = a0 + b0;
    *(f4*)(go + mb + 16) = a1 + b1;
    *(f4*)(go + mb + 32) = a2 + b2;
    *(f4*)(go + mb + 48) = a3 + b3;
}

// ---------------- GRU v13: dot4, 256 lanes * 3 rows/lane, 1 barrier/step ----------------
// v12 post-mortem: 192 wave-uniform ds_read_b128/step (16/lane x 12 waves) serialized the LDS
// pipe (~8cy each broadcast-fanout) = ~1550cy/step. Fix: 4 waves only (16 reads/wave -> 64/step),
// each lane owns h[j] AND all 3 gate rows {j,256+j,512+j} (192 VGPRs, launch_bounds(256,1):
// 1 wave/SIMD, <=450 VGPR no-spill). Gate update is now lane-local -> sums exchange + 2nd
// barrier GONE. One raw barrier/step (lgkmcnt only, no vmcnt drain) so the 1-step-ahead gi
// register prefetch rides across it.
__global__ void __launch_bounds__(256, 1) k_gru(
                      const signed char* __restrict__ Wq, const float* __restrict__ rowscale,
                      const float* __restrict__ bhh,
                      const float* __restrict__ gi, const float* __restrict__ h0,
                      const float* __restrict__ tv,
                      const float* __restrict__ gateW, const float* __restrict__ gateU,
                      const float* __restrict__ gateb,
                      const float* __restrict__ outW, const float* __restrict__ outb,
                      float* __restrict__ out) {
    __shared__ __align__(16) int qd[2][64];   // h as 64 packed-i8 dwords, ping-pong
    __shared__ float hts[HD];
    __shared__ float sgs[512];
    __shared__ float vvs[HD];
    __shared__ float lg[8];

    int tid = threadIdx.x;
    int j = tid;                   // lane owns h[j] and rows j (r), 256+j (z), 512+j (n)

    // this lane's 3 weight rows: 48 x i4 = 192 VGPRs, resident for all 1024 steps
    i4 wr_[16], wz_[16], wn_[16];
    {
        const signed char* pr = Wq + (long)j * HD;
        const signed char* pz = Wq + (long)(256 + j) * HD;
        const signed char* pn = Wq + (long)(512 + j) * HD;
#pragma unroll
        for (int c = 0; c < 16; ++c) {
            wr_[c] = *(const i4*)(pr + c * 16);
            wz_[c] = *(const i4*)(pz + c * 16);
            wn_[c] = *(const i4*)(pn + c * 16);
        }
    }
    float rs_r = rowscale[j];
    float rs_z = rowscale[256 + j];
    float rs_n = rowscale[512 + j];
    float bn = bhh[512 + j];

    float hv = h0[j];
    {
        float hc = fminf(fmaxf(hv, -SH), SH);
        ((signed char*)qd[0])[j] = (signed char)(int)rintf(hc * (127.f / SH));
    }
    // prime gi prefetch for t=0 (stays in flight across the raw barrier)
    float pgr, pgz, pgn;
    {
        const float* g = gi + j;
        pgr = g[0]; pgz = g[256]; pgn = g[512];
    }
    asm volatile("s_waitcnt lgkmcnt(0)" ::: "memory");
    __builtin_amdgcn_s_barrier();

    for (int t = 0; t < NS; ++t) {
        int p = t & 1;
        float gr = pgr, gz = pgz, gn = pgn;
        // prefetch next step's gi (addresses depend only on t; consumed after next barrier)
        {
            long tn = (t + 1 < NS) ? (long)(t + 1) : (long)(NS - 1);
            const float* g = gi + tn * TH + j;
            pgr = g[0]; pgz = g[256]; pgn = g[512];
        }
        int ar = 0, az = 0, an = 0;
#pragma unroll
        for (int c = 0; c < 16; ++c) {
            i4 hb = *(const i4*)&qd[p][c * 4];   // wave-uniform broadcast read
            ar = dot4(hb[0], wr_[c][0], ar);
            ar = dot4(hb[1], wr_[c][1], ar);
            ar = dot4(hb[2], wr_[c][2], ar);
            ar = dot4(hb[3], wr_[c][3], ar);
            az = dot4(hb[0], wz_[c][0], az);
            az = dot4(hb[1], wz_[c][1], az);
            az = dot4(hb[2], wz_[c][2], az);
            az = dot4(hb[3], wz_[c][3], az);
            an = dot4(hb[0], wn_[c][0], an);
            an = dot4(hb[1], wn_[c][1], an);
            an = dot4(hb[2], wn_[c][2], an);
            an = dot4(hb[3], wn_[c][3], an);
        }
        // lane-local gate update (no cross-lane exchange needed)
        float rv = sigm(gr + (float)ar * rs_r);
        float zv = sigm(gz + (float)az * rs_z);
        float nv = tanh_(gn + rv * ((float)an * rs_n + bn));
        hv = (1.f - zv) * nv + zv * hv;
        float hc = fminf(fmaxf(hv, -SH), SH);
        ((signed char*)qd[p ^ 1])[j] = (signed char)(int)rintf(hc * (127.f / SH));
        // LDS-visibility barrier only (no vmcnt drain -> gi prefetch stays in flight)
        asm volatile("s_waitcnt lgkmcnt(0)" ::: "memory");
        __builtin_amdgcn_s_barrier();
    }

    // head (256 threads)
    hts[j] = hv;
    __syncthreads();
    for (int r = tid; r < 512; r += 256) {
        float s = gateb[r];
        for (int k = 0; k < HD; ++k)
            s += gateW[r * HD + k] * hts[k] + gateU[r * HD + k] * tv[k];
        sgs[r] = sigm(s);
    }
    __syncthreads();
    vvs[tid] = tanh_(sgs[tid] * hts[tid] + sgs[256 + tid] * tv[tid]);
    __syncthreads();
    if (tid < 5) {
        float s = outb[tid];
        for (int k = 0; k < HD; ++k) s += outW[tid * HD + k] * vvs[k];
        lg[tid] = s;
    }
    __syncthreads();
    if (tid == 0) {
        float m = lg[0];
        for (int i = 1; i < 5; ++i) m = fmaxf(m, lg[i]);
        float e[5], sum = 0.f;
        for (int i = 0; i < 5; ++i) { e[i] = __expf(lg[i] - m); sum += e[i]; }
        for (int i = 0; i < 5; ++i) out[i] = e[i] / sum;
    }
}

extern "C" void kernel_launch(void* const* d_in, const int* in_sizes, int n_in,
                              void* d_out, int out_size, void* d_ws, size_t ws_size,
                              hipStream_t stream) {
    (void)in_sizes; (void)n_in; (void)out_size; (void)ws_size;
    const int* sIdx = (const int*)d_in[0];
    const int* depT = (const int*)d_in[1];
    const float* DT = (const float*)d_in[2];
    const float* h0 = (const float*)d_in[3];
    const float* emb = (const float*)d_in[4];
    const float* q = (const float*)d_in[5];
    const float* W = (const float*)d_in[6];
    const float* U = (const float*)d_in[7];
    const float* Dm = (const float*)d_in[8];
    const float* b = (const float*)d_in[9];
    const float* Wih = (const float*)d_in[10];
    const float* Whh = (const float*)d_in[11];
    const float* bih = (const float*)d_in[12];
    const float* bhh = (const float*)d_in[13];
    const float* gateW = (const float*)d_in[14];
    const float* gateU = (const float*)d_in[15];
    const float* gateb = (const float*)d_in[16];
    const float* mlpW = (const float*)d_in[17];
    const float* mlpb = (const float*)d_in[18];
    const float* outW = (const float*)d_in[19];
    const float* outb = (const float*)d_in[20];

    char* ws = (char*)d_ws;
    unsigned short* Wb = (unsigned short*)ws;   ws += 768 * 320 * 2;
    _Float16* Uh = (_Float16*)ws;               ws += 768 * 256 * 2;
    _Float16* Wihh = (_Float16*)ws;             ws += 768 * 256 * 2;
    signed char* Wq = (signed char*)ws;         ws += 768 * 256;
    float* rowscale = (float*)ws;               ws += 768 * 4;
    float* bias2 = (float*)ws;                  ws += 768 * 4;
    float* Dq = (float*)ws;                     ws += 10 * 768 * 4;
    float* tv = (float*)ws;                     ws += 1024;
    ws = (char*)d_ws + ((((size_t)(ws - (char*)d_ws)) + 4095) & ~(size_t)4095);
    unsigned short* pre = (unsigned short*)ws;  ws += (size_t)65536 * 768 * 2;
    float* gi = (float*)ws;                     ws += (size_t)1024 * 768 * 4;

    k_prep<<<dim3(799), dim3(256), 0, stream>>>(W, U, Wih, Whh, q, Dm, DT, mlpW, mlpb,
                                                bih, bhh,
                                                Wb, Uh, Wihh, Wq, rowscale, bias2, Dq, tv);
    k_phaseB<<<dim3(2048), dim3(256), 0, stream>>>(sIdx, depT, emb, Wb, Dq, b, pre);
    k_phaseC<<<dim3(64), dim3(768), 0, stream>>>(pre, Uh, Wihh, bias2, gi);
    k_gru<<<dim3(1), dim3(256), 0, stream>>>(Wq, rowscale, bhh, gi, h0, tv,
                                             gateW, gateU, gateb, outW, outb, (float*)d_out);
}

// Round 5
// 1295.930 us; speedup vs baseline: 1.3034x; 1.0219x over previous
//
#include <hip/hip_runtime.h>

typedef short short8 __attribute__((ext_vector_type(8)));
typedef float f4 __attribute__((ext_vector_type(4)));
typedef int i4 __attribute__((ext_vector_type(4)));
typedef _Float16 half8 __attribute__((ext_vector_type(8)));
typedef _Float16 h2 __attribute__((ext_vector_type(2)));

#define HD 256
#define ED 300
#define EP 320
#define TH 768
#define NS 1024
#define LW 64
#define SH 4.5f

__device__ __forceinline__ unsigned short f2bf(float f) {
    unsigned int u = __float_as_uint(f);
    u = (u + 0x7FFFu + ((u >> 16) & 1u)) >> 16;
    return (unsigned short)u;
}
__device__ __forceinline__ float bf2f(unsigned short s) {
    return __uint_as_float(((unsigned int)s) << 16);
}
__device__ __forceinline__ float sigm(float x) {
    return __builtin_amdgcn_rcpf(1.f + __expf(-x));
}
__device__ __forceinline__ float tanh_(float x) {
    x = fminf(fmaxf(x, -15.f), 15.f);
    return 1.f - 2.f * __builtin_amdgcn_rcpf(1.f + __expf(2.f * x));
}
__device__ __forceinline__ unsigned int pack_h2(float a, float b) {
    h2 p; p.x = (_Float16)a; p.y = (_Float16)b;
    return __builtin_bit_cast(unsigned int, p);
}

__device__ __forceinline__ void load8bf(const unsigned short* p, float* o) {
    uint4 a = *(const uint4*)p;
    o[0] = bf2f((unsigned short)(a.x & 0xffff)); o[1] = bf2f((unsigned short)(a.x >> 16));
    o[2] = bf2f((unsigned short)(a.y & 0xffff)); o[3] = bf2f((unsigned short)(a.y >> 16));
    o[4] = bf2f((unsigned short)(a.z & 0xffff)); o[5] = bf2f((unsigned short)(a.z >> 16));
    o[6] = bf2f((unsigned short)(a.w & 0xffff)); o[7] = bf2f((unsigned short)(a.w >> 16));
}
__device__ __forceinline__ void ubf4(uint2 a, float* o) {
    o[0] = bf2f((unsigned short)(a.x & 0xffff)); o[1] = bf2f((unsigned short)(a.x >> 16));
    o[2] = bf2f((unsigned short)(a.y & 0xffff)); o[3] = bf2f((unsigned short)(a.y >> 16));
}

// i8 dot4: d = sum(a.i8[i]*b.i8[i]) + c  (exact integer math)
__device__ __forceinline__ int dot4(int a, int b, int c) {
#if __has_builtin(__builtin_amdgcn_sdot4)
    return __builtin_amdgcn_sdot4(a, b, c, false);
#else
    int s = c;
    s += (int)(signed char)(a & 0xff)        * (int)(signed char)(b & 0xff);
    s += (int)(signed char)((a >> 8) & 0xff) * (int)(signed char)((b >> 8) & 0xff);
    s += (int)(signed char)((a >> 16) & 0xff)* (int)(signed char)((b >> 16) & 0xff);
    s += (int)(signed char)((a >> 24) & 0xff)* (int)(signed char)((b >> 24) & 0xff);
    return s;
#endif
}

// opaque 16B global load: result produced by asm -> compiler CANNOT rematerialize the load,
// so the value must stay register-resident across the step loop (the v12/v13 failure mode).
__device__ __forceinline__ i4 gload16(const signed char* p) {
    i4 r;
    asm volatile("global_load_dwordx4 %0, %1, off\n\ts_waitcnt vmcnt(0)"
                 : "=v"(r) : "v"(p));
    return r;
}

// ---------------- prep: weight conversions, i8 quantization (ALL 768 Whh rows), Dq, topic ----------------
__global__ void k_prep(const float* __restrict__ W, const float* __restrict__ U,
                       const float* __restrict__ Wih, const float* __restrict__ Whh,
                       const float* __restrict__ q, const float* __restrict__ Dm,
                       const float* __restrict__ DT, const float* __restrict__ mlpW,
                       const float* __restrict__ mlpb,
                       const float* __restrict__ bih, const float* __restrict__ bhh,
                       unsigned short* __restrict__ Wb, _Float16* __restrict__ Uh,
                       _Float16* __restrict__ Wihh,
                       signed char* __restrict__ Wq, float* __restrict__ rowscale,
                       float* __restrict__ bias2,
                       float* __restrict__ Dq, float* __restrict__ tv) {
    __shared__ float smax[4];
    int bid = blockIdx.x, tid = threadIdx.x;
    if (bid < 768) {
        int r = bid;
        for (int j = tid; j < EP; j += 256)
            Wb[r * EP + j] = (j < ED) ? f2bf(W[r * ED + j]) : (unsigned short)0;
        float whv = Whh[r * HD + tid];
        for (int j = tid; j < HD; j += 256) {
            Uh[r * HD + j] = (_Float16)U[r * HD + j];
            Wihh[r * HD + j] = (_Float16)Wih[r * HD + j];
        }
        // per-row i8 quantization of ALL Whh rows
        float v = fabsf(whv);
        for (int o = 32; o; o >>= 1) v = fmaxf(v, __shfl_xor(v, o));
        if ((tid & 63) == 0) smax[tid >> 6] = v;
        __syncthreads();
        float am = fmaxf(fmaxf(smax[0], smax[1]), fmaxf(smax[2], smax[3]));
        float inv = (am > 0.f) ? 127.f / am : 0.f;
        int qi = (int)rintf(whv * inv);
        qi = max(-127, min(127, qi));
        Wq[r * HD + tid] = (signed char)qi;
        if (tid == 0) rowscale[r] = (am / 127.f) * (SH / 127.f);
    } else if (bid < 798) {
        int idx = bid - 768;
        int d = idx / 3, part = idx - d * 3;
        int n = part * 256 + tid;
        float s = 0.f;
        for (int h = 0; h < HD; ++h) s += Dm[n * HD + h] * q[d * HD + h];
        Dq[d * TH + n] = s;
    } else {
        if (tid < HD) {
            float s = 0.f;
            for (int k = 0; k < 100; ++k) s += mlpW[tid * 100 + k] * DT[k];
            tv[tid] = tanh_(s + mlpb[tid]);
        }
        for (int r = tid; r < TH; r += 256)
            bias2[r] = bih[r] + ((r < 512) ? bhh[r] : 0.f);
    }
}

// ---------------- phase B v2: x staged once in LDS as bf16; K-loop = ds_read + MFMA only ----------------
#define XP 328   // padded LDS row stride (elements); 328*2B/4 = 164 dwords, %32=4 -> 2-way alias (free)
__launch_bounds__(256, 2)
__global__ void k_phaseB(const int* __restrict__ sIdx, const int* __restrict__ depT,
                         const float* __restrict__ emb, const unsigned short* __restrict__ Wb,
                         const float* __restrict__ Dq, const float* __restrict__ bias,
                         unsigned short* __restrict__ pre) {
    __shared__ float dq_s[10 * 772];
    __shared__ float b_s[TH];
    __shared__ int dep_s[32];
    __shared__ int idx_s[32];
    __shared__ __align__(16) unsigned short xbf[32 * XP];
    int tid = threadIdx.x;
    int c0 = blockIdx.x * 32;
    for (int i = tid; i < 10 * 768; i += 256) {
        int d = i / 768, n = i - d * 768;
        dq_s[d * 772 + n] = Dq[i];
    }
    for (int i = tid; i < TH; i += 256) b_s[i] = bias[i];
    if (tid < 32) {
        int m = c0 + tid;
        idx_s[tid] = sIdx[m];
        int l = m & 63, s = m >> 6;
        dep_s[tid] = (l == 63) ? 9 : depT[s * 63 + l];
    }
    __syncthreads();
    // stage 32 gathered x rows as bf16 (coalesced within a row)
    for (int i = tid; i < 32 * EP; i += 256) {
        int row = i / EP, col = i - row * EP;
        unsigned short v = 0;
        if (col < ED) v = f2bf(emb[(long)idx_s[row] * ED + col]);
        xbf[row * XP + col] = v;
    }
    __syncthreads();

    int lane = tid & 63;
    int w = tid >> 6;
    int quad = lane >> 4, l16 = lane & 15;

    f4 acc[2][12];
#pragma unroll
    for (int cs = 0; cs < 2; ++cs)
#pragma unroll
        for (int ms = 0; ms < 12; ++ms) acc[cs][ms] = (f4){0.f, 0.f, 0.f, 0.f};

    const unsigned short* wbase = Wb + (w * 192 + l16) * EP;

#pragma unroll
    for (int kt = 0; kt < 10; ++kt) {
        int k0 = kt * 32 + quad * 8;
        short8 bf0 = *(const short8*)&xbf[l16 * XP + k0];
        short8 bf1 = *(const short8*)&xbf[(16 + l16) * XP + k0];
#pragma unroll
        for (int ms = 0; ms < 12; ++ms) {
            short8 af = *(const short8*)(wbase + ms * 16 * EP + k0);
            acc[0][ms] = __builtin_amdgcn_mfma_f32_16x16x32_bf16(af, bf0, acc[0][ms], 0, 0, 0);
            acc[1][ms] = __builtin_amdgcn_mfma_f32_16x16x32_bf16(af, bf1, acc[1][ms], 0, 0, 0);
        }
    }

#pragma unroll
    for (int cs = 0; cs < 2; ++cs) {
        int xr = c0 + cs * 16 + l16;
        int dep = dep_s[cs * 16 + l16];
        unsigned short* prow = pre + (long)xr * TH;
#pragma unroll
        for (int ms = 0; ms < 12; ++ms) {
            int ncol = w * 192 + ms * 16 + quad * 4;
            f4 dq4 = *(const f4*)&dq_s[dep * 772 + ncol];
            f4 b4 = *(const f4*)&b_s[ncol];
            unsigned int lo = (unsigned int)f2bf(acc[cs][ms][0] + dq4[0] + b4[0]) |
                              ((unsigned int)f2bf(acc[cs][ms][1] + dq4[1] + b4[1]) << 16);
            unsigned int hi = (unsigned int)f2bf(acc[cs][ms][2] + dq4[2] + b4[2]) |
                              ((unsigned int)f2bf(acc[cs][ms][3] + dq4[3] + b4[3]) << 16);
            uint2 v; v.x = lo; v.y = hi;
            *(uint2*)(prow + ncol) = v;
        }
    }
}

// ---------------- phase C: U AGPR-resident MFMA, 16 sentences/WG, pre-loads hoisted ----------------
__global__ void __launch_bounds__(768) k_phaseC(
                         const unsigned short* __restrict__ pre,
                         const _Float16* __restrict__ Uh,
                         const _Float16* __restrict__ Wihh,
                         const float* __restrict__ bias2,
                         float* __restrict__ gi) {
    __shared__ __align__(16) uint4 hfr[512];
    __shared__ __align__(16) float tot[16 * 772];
    int tid = threadIdx.x;
    int lane = tid & 63, w = tid >> 6, quad = lane >> 4, l16 = lane & 15;
    int s0 = blockIdx.x * 16;

    uint4 frag[32];
    {
        const _Float16* base = Uh + (w * 64 + l16) * HD;
#pragma unroll
        for (int t = 0; t < 4; ++t)
#pragma unroll
            for (int kt = 0; kt < 8; ++kt)
                frag[t * 8 + kt] = *(const uint4*)(base + t * 16 * HD + kt * 32 + quad * 8);
    }

    int us = tid >> 5;
    int jg = tid & 31;
    int j0 = jg * 8;
    int hcell = (j0 >> 5) * 64 + 16 * ((j0 >> 3) & 3) + us;
    uint4 hcp;

    if (tid < 512) {
        const unsigned short* prow = pre + ((long)(s0 + us) * LW + 63) * TH;
        float iv[8], uv[8], hcv[8];
        load8bf(prow + 256 + j0, iv);
        load8bf(prow + 512 + j0, uv);
#pragma unroll
        for (int r = 0; r < 8; ++r) hcv[r] = tanh_(sigm(iv[r]) * tanh_(uv[r]));
        hcp.x = pack_h2(hcv[0], hcv[1]); hcp.y = pack_h2(hcv[2], hcv[3]);
        hcp.z = pack_h2(hcv[4], hcv[5]); hcp.w = pack_h2(hcv[6], hcv[7]);
        hfr[hcell] = hcp;
    }
    __syncthreads();

    int mb = w * 64 + quad * 4;

    for (int step = 0; step < 63; ++step) {
        int l = 62 - step;
        uint2 praw[6];
        if (tid < 512) {
            const unsigned short* prow = pre + ((long)(s0 + us) * LW + l) * TH;
#pragma unroll
            for (int g = 0; g < 3; ++g) {
                praw[2 * g]     = *(const uint2*)(prow + g * 256 + j0);
                praw[2 * g + 1] = *(const uint2*)(prow + g * 256 + j0 + 4);
            }
        }
        f4 a0 = (f4){0,0,0,0}, a1 = (f4){0,0,0,0}, a2 = (f4){0,0,0,0}, a3 = (f4){0,0,0,0};
#pragma unroll
        for (int kt = 0; kt < 8; ++kt) {
            half8 b = __builtin_bit_cast(half8, hfr[kt * 64 + lane]);
            a0 = __builtin_amdgcn_mfma_f32_16x16x32_f16(__builtin_bit_cast(half8, frag[kt]), b, a0, 0, 0, 0);
            a1 = __builtin_amdgcn_mfma_f32_16x16x32_f16(__builtin_bit_cast(half8, frag[8 + kt]), b, a1, 0, 0, 0);
            a2 = __builtin_amdgcn_mfma_f32_16x16x32_f16(__builtin_bit_cast(half8, frag[16 + kt]), b, a2, 0, 0, 0);
            a3 = __builtin_amdgcn_mfma_f32_16x16x32_f16(__builtin_bit_cast(half8, frag[24 + kt]), b, a3, 0, 0, 0);
        }
        float* tr = tot + l16 * 772;
        *(f4*)&tr[mb] = a0;
        *(f4*)&tr[mb + 16] = a1;
        *(f4*)&tr[mb + 32] = a2;
        *(f4*)&tr[mb + 48] = a3;
        __syncthreads();
        if (tid < 512) {
            const float* ts = tot + us * 772;
            float hcv[8];
            h2 px = __builtin_bit_cast(h2, hcp.x); h2 py = __builtin_bit_cast(h2, hcp.y);
            h2 pz = __builtin_bit_cast(h2, hcp.z); h2 pw = __builtin_bit_cast(h2, hcp.w);
            hcv[0] = (float)px.x; hcv[1] = (float)px.y; hcv[2] = (float)py.x; hcv[3] = (float)py.y;
            hcv[4] = (float)pz.x; hcv[5] = (float)pz.y; hcv[6] = (float)pw.x; hcv[7] = (float)pw.y;
#pragma unroll
            for (int hf = 0; hf < 2; ++hf) {
                int jb = j0 + hf * 4;
                float pf[4], pi_[4], pu[4];
                ubf4(praw[hf], pf);
                ubf4(praw[2 + hf], pi_);
                ubf4(praw[4 + hf], pu);
                f4 tf = *(const f4*)&ts[jb];
                f4 ti = *(const f4*)&ts[256 + jb];
                f4 tu = *(const f4*)&ts[512 + jb];
#pragma unroll
                for (int r = 0; r < 4; ++r) {
                    float ff = tf[r] + pf[r];
                    float ii = ti[r] + pi_[r];
                    float uu = tu[r] + pu[r];
                    hcv[hf * 4 + r] = tanh_(sigm(ii) * tanh_(uu) + sigm(ff) * hcv[hf * 4 + r]);
                }
            }
            hcp.x = pack_h2(hcv[0], hcv[1]); hcp.y = pack_h2(hcv[2], hcv[3]);
            hcp.z = pack_h2(hcv[4], hcv[5]); hcp.w = pack_h2(hcv[6], hcv[7]);
            hfr[hcell] = hcp;
        }
        __syncthreads();
    }

    {
        const _Float16* base = Wihh + (w * 64 + l16) * HD;
#pragma unroll
        for (int t = 0; t < 4; ++t)
#pragma unroll
            for (int kt = 0; kt < 8; ++kt)
                frag[t * 8 + kt] = *(const uint4*)(base + t * 16 * HD + kt * 32 + quad * 8);
    }
    f4 a0 = (f4){0,0,0,0}, a1 = (f4){0,0,0,0}, a2 = (f4){0,0,0,0}, a3 = (f4){0,0,0,0};
#pragma unroll
    for (int kt = 0; kt < 8; ++kt) {
        half8 b = __builtin_bit_cast(half8, hfr[kt * 64 + lane]);
        a0 = __builtin_amdgcn_mfma_f32_16x16x32_f16(__builtin_bit_cast(half8, frag[kt]), b, a0, 0, 0, 0);
        a1 = __builtin_amdgcn_mfma_f32_16x16x32_f16(__builtin_bit_cast(half8, frag[8 + kt]), b, a1, 0, 0, 0);
        a2 = __builtin_amdgcn_mfma_f32_16x16x32_f16(__builtin_bit_cast(half8, frag[16 + kt]), b, a2, 0, 0, 0);
        a3 = __builtin_amdgcn_mfma_f32_16x16x32_f16(__builtin_bit_cast(half8, frag[24 + kt]), b, a3, 0, 0, 0);
    }
    float* go = gi + (long)(s0 + l16) * TH;
    f4 b0 = *(const f4*)(bias2 + mb);
    f4 b1 = *(const f4*)(bias2 + mb + 16);
    f4 b2 = *(const f4*)(bias2 + mb + 32);
    f4 b3 = *(const f4*)(bias2 + mb + 48);
    *(f4*)(go + mb) = a0 + b0;
    *(f4*)(go + mb + 16) = a1 + b1;
    *(f4*)(go + mb + 32) = a2 + b2;
    *(f4*)(go + mb + 48) = a3 + b3;
}

// ---------------- GRU v14: v13 + asm-opaque weight loads (force register residency) ----------------
// v13 post-mortem: VGPR_Count=128 < 192 needed -> compiler rematerialized the loop-invariant
// weight loads, re-fetching 192KB of Wq from L2 EVERY step (~1500-3000cy) = the whole step time.
// Fix: load weights via inline-asm global_load_dwordx4 (result of asm cannot be rematerialized,
// must stay in VGPRs). Verify via VGPR_Count ~280-320. Rest of v13 unchanged: lane-local gates,
// 1 raw barrier/step (lgkmcnt only), 1-step gi register prefetch riding across it.
__global__ void __launch_bounds__(256, 1) k_gru(
                      const signed char* __restrict__ Wq, const float* __restrict__ rowscale,
                      const float* __restrict__ bhh,
                      const float* __restrict__ gi, const float* __restrict__ h0,
                      const float* __restrict__ tv,
                      const float* __restrict__ gateW, const float* __restrict__ gateU,
                      const float* __restrict__ gateb,
                      const float* __restrict__ outW, const float* __restrict__ outb,
                      float* __restrict__ out) {
    __shared__ __align__(16) int qd[2][64];   // h as 64 packed-i8 dwords, ping-pong
    __shared__ float hts[HD];
    __shared__ float sgs[512];
    __shared__ float vvs[HD];
    __shared__ float lg[8];

    int tid = threadIdx.x;
    int j = tid;                   // lane owns h[j] and rows j (r), 256+j (z), 512+j (n)

    // this lane's 3 weight rows: 48 x i4 = 192 VGPRs, asm-opaque -> register-resident
    i4 wr_[16], wz_[16], wn_[16];
    {
        const signed char* pr = Wq + (long)j * HD;
        const signed char* pz = Wq + (long)(256 + j) * HD;
        const signed char* pn = Wq + (long)(512 + j) * HD;
#pragma unroll
        for (int c = 0; c < 16; ++c) {
            wr_[c] = gload16(pr + c * 16);
            wz_[c] = gload16(pz + c * 16);
            wn_[c] = gload16(pn + c * 16);
        }
    }
    float rs_r = rowscale[j];
    float rs_z = rowscale[256 + j];
    float rs_n = rowscale[512 + j];
    float bn = bhh[512 + j];

    float hv = h0[j];
    {
        float hc = fminf(fmaxf(hv, -SH), SH);
        ((signed char*)qd[0])[j] = (signed char)(int)rintf(hc * (127.f / SH));
    }
    // prime gi prefetch for t=0 (stays in flight across the raw barrier)
    float pgr, pgz, pgn;
    {
        const float* g = gi + j;
        pgr = g[0]; pgz = g[256]; pgn = g[512];
    }
    asm volatile("s_waitcnt lgkmcnt(0)" ::: "memory");
    __builtin_amdgcn_s_barrier();

    for (int t = 0; t < NS; ++t) {
        int p = t & 1;
        float gr = pgr, gz = pgz, gn = pgn;
        // prefetch next step's gi (addresses depend only on t; consumed after next barrier)
        {
            long tn = (t + 1 < NS) ? (long)(t + 1) : (long)(NS - 1);
            const float* g = gi + tn * TH + j;
            pgr = g[0]; pgz = g[256]; pgn = g[512];
        }
        int ar = 0, az = 0, an = 0;
#pragma unroll
        for (int c = 0; c < 16; ++c) {
            i4 hb = *(const i4*)&qd[p][c * 4];   // wave-uniform broadcast read
            ar = dot4(hb[0], wr_[c][0], ar);
            ar = dot4(hb[1], wr_[c][1], ar);
            ar = dot4(hb[2], wr_[c][2], ar);
            ar = dot4(hb[3], wr_[c][3], ar);
            az = dot4(hb[0], wz_[c][0], az);
            az = dot4(hb[1], wz_[c][1], az);
            az = dot4(hb[2], wz_[c][2], az);
            az = dot4(hb[3], wz_[c][3], az);
            an = dot4(hb[0], wn_[c][0], an);
            an = dot4(hb[1], wn_[c][1], an);
            an = dot4(hb[2], wn_[c][2], an);
            an = dot4(hb[3], wn_[c][3], an);
        }
        // lane-local gate update (no cross-lane exchange needed)
        float rv = sigm(gr + (float)ar * rs_r);
        float zv = sigm(gz + (float)az * rs_z);
        float nv = tanh_(gn + rv * ((float)an * rs_n + bn));
        hv = (1.f - zv) * nv + zv * hv;
        float hc = fminf(fmaxf(hv, -SH), SH);
        ((signed char*)qd[p ^ 1])[j] = (signed char)(int)rintf(hc * (127.f / SH));
        // LDS-visibility barrier only (no vmcnt drain -> gi prefetch stays in flight)
        asm volatile("s_waitcnt lgkmcnt(0)" ::: "memory");
        __builtin_amdgcn_s_barrier();
    }

    // head (256 threads)
    hts[j] = hv;
    __syncthreads();
    for (int r = tid; r < 512; r += 256) {
        float s = gateb[r];
        for (int k = 0; k < HD; ++k)
            s += gateW[r * HD + k] * hts[k] + gateU[r * HD + k] * tv[k];
        sgs[r] = sigm(s);
    }
    __syncthreads();
    vvs[tid] = tanh_(sgs[tid] * hts[tid] + sgs[256 + tid] * tv[tid]);
    __syncthreads();
    if (tid < 5) {
        float s = outb[tid];
        for (int k = 0; k < HD; ++k) s += outW[tid * HD + k] * vvs[k];
        lg[tid] = s;
    }
    __syncthreads();
    if (tid == 0) {
        float m = lg[0];
        for (int i = 1; i < 5; ++i) m = fmaxf(m, lg[i]);
        float e[5], sum = 0.f;
        for (int i = 0; i < 5; ++i) { e[i] = __expf(lg[i] - m); sum += e[i]; }
        for (int i = 0; i < 5; ++i) out[i] = e[i] / sum;
    }
}

extern "C" void kernel_launch(void* const* d_in, const int* in_sizes, int n_in,
                              void* d_out, int out_size, void* d_ws, size_t ws_size,
                              hipStream_t stream) {
    (void)in_sizes; (void)n_in; (void)out_size; (void)ws_size;
    const int* sIdx = (const int*)d_in[0];
    const int* depT = (const int*)d_in[1];
    const float* DT = (const float*)d_in[2];
    const float* h0 = (const float*)d_in[3];
    const float* emb = (const float*)d_in[4];
    const float* q = (const float*)d_in[5];
    const float* W = (const float*)d_in[6];
    const float* U = (const float*)d_in[7];
    const float* Dm = (const float*)d_in[8];
    const float* b = (const float*)d_in[9];
    const float* Wih = (const float*)d_in[10];
    const float* Whh = (const float*)d_in[11];
    const float* bih = (const float*)d_in[12];
    const float* bhh = (const float*)d_in[13];
    const float* gateW = (const float*)d_in[14];
    const float* gateU = (const float*)d_in[15];
    const float* gateb = (const float*)d_in[16];
    const float* mlpW = (const float*)d_in[17];
    const float* mlpb = (const float*)d_in[18];
    const float* outW = (const float*)d_in[19];
    const float* outb = (const float*)d_in[20];

    char* ws = (char*)d_ws;
    unsigned short* Wb = (unsigned short*)ws;   ws += 768 * 320 * 2;
    _Float16* Uh = (_Float16*)ws;               ws += 768 * 256 * 2;
    _Float16* Wihh = (_Float16*)ws;             ws += 768 * 256 * 2;
    signed char* Wq = (signed char*)ws;         ws += 768 * 256;
    float* rowscale = (float*)ws;               ws += 768 * 4;
    float* bias2 = (float*)ws;                  ws += 768 * 4;
    float* Dq = (float*)ws;                     ws += 10 * 768 * 4;
    float* tv = (float*)ws;                     ws += 1024;
    ws = (char*)d_ws + ((((size_t)(ws - (char*)d_ws)) + 4095) & ~(size_t)4095);
    unsigned short* pre = (unsigned short*)ws;  ws += (size_t)65536 * 768 * 2;
    float* gi = (float*)ws;                     ws += (size_t)1024 * 768 * 4;

    k_prep<<<dim3(799), dim3(256), 0, stream>>>(W, U, Wih, Whh, q, Dm, DT, mlpW, mlpb,
                                                bih, bhh,
                                                Wb, Uh, Wihh, Wq, rowscale, bias2, Dq, tv);
    k_phaseB<<<dim3(2048), dim3(256), 0, stream>>>(sIdx, depT, emb, Wb, Dq, b, pre);
    k_phaseC<<<dim3(64), dim3(768), 0, stream>>>(pre, Uh, Wihh, bias2, gi);
    k_gru<<<dim3(1), dim3(256), 0, stream>>>(Wq, rowscale, bhh, gi, h0, tv,
                                             gateW, gateU, gateb, outW, outb, (float*)d_out);
}